// Round 3
// baseline (1715.451 us; speedup 1.0000x reference)
//
#include <hip/hip_runtime.h>
#include <math.h>

#define NN 10000
#define NE 160000
#define NG 64
#define NT 5
#define NL 4
#define ADL 2.833213344056216f

// ws layout (float offsets)
#define OFF_H      0
#define OFF_HC     750000
#define OFF_P      1500000
#define OFF_Q      5250000
#define OFF_AGG    9000000
#define OFF_RLUT   24000000
#define OFF_INVDEG 24006000
#define OFF_AMP    24016000
#define OFF_ATT    24026000
#define OFF_STATS  24036000
#define OFF_GPOOL  24036160
#define OFF_WPAD   24040960
#define OFF_INT    24118960

__global__ void k_zero_cnt(int* cnt){
    int i = blockIdx.x*256 + threadIdx.x;
    if (i < NN) cnt[i] = 0;
}

// h0 = node_emb[x].reshape(N,150) @ pre_lin_W + b
__global__ __launch_bounds__(256) void k_h0(const int* __restrict__ x,
        const float* __restrict__ node_emb, const float* __restrict__ plW,
        const float* __restrict__ plb, float* __restrict__ h){
    __shared__ float s_emb[21*75];
    __shared__ float s_W[150*75];
    __shared__ float s_b[75];
    int tid = threadIdx.x;
    for (int i = tid; i < 21*75; i += 256) s_emb[i] = node_emb[i];
    for (int i = tid; i < 150*75; i += 256) s_W[i] = plW[i];
    if (tid < 75) s_b[tid] = plb[tid];
    __syncthreads();
    for (int out = blockIdx.x*256 + tid; out < NN*75; out += gridDim.x*256){
        int n = out / 75, f = out - n*75;
        int x0 = x[2*n], x1 = x[2*n+1];
        float acc = s_b[f];
        const float* e0 = s_emb + x0*75;
        const float* e1 = s_emb + x1*75;
        #pragma unroll 5
        for (int k = 0; k < 75; k++)
            acc += e0[k]*s_W[k*75+f] + e1[k]*s_W[(75+k)*75+f];
        h[out] = acc;
    }
}

__global__ void k_hist(const int* __restrict__ ei, int* __restrict__ cnt){
    int e = blockIdx.x*256 + threadIdx.x;
    if (e < NE) atomicAdd(&cnt[ei[NE + e]], 1);
}

// single-block prefix sum: eoff[0]=0, eoff[n+1]=inclusive prefix
__global__ void k_scan(const int* __restrict__ cnt, int* __restrict__ eoff){
    __shared__ int buf[256];
    __shared__ int carry;
    int tid = threadIdx.x;
    if (tid == 0){ carry = 0; eoff[0] = 0; }
    __syncthreads();
    for (int base = 0; base < NN; base += 256){
        int v = (base + tid < NN) ? cnt[base + tid] : 0;
        buf[tid] = v; __syncthreads();
        for (int off = 1; off < 256; off <<= 1){
            int t2 = (tid >= off) ? buf[tid - off] : 0;
            __syncthreads();
            buf[tid] += t2;
            __syncthreads();
        }
        int inc = buf[tid] + carry;
        if (base + tid < NN) eoff[base + tid + 1] = inc;
        __syncthreads();
        if (tid == 255) carry = inc;
        __syncthreads();
    }
}

__global__ void k_nodestats(const int* __restrict__ cnt, const int* __restrict__ eoff,
        float* __restrict__ invdeg, float* __restrict__ amp, float* __restrict__ att,
        int* __restrict__ cursor){
    int n = blockIdx.x*256 + threadIdx.x;
    if (n >= NN) return;
    int c = cnt[n];
    cursor[n] = eoff[n];
    float cf = (float)c;
    float dg = cf < 1.f ? 1.f : cf;
    invdeg[n] = 1.f / dg;
    float ld = logf(dg + 1.f);
    amp[n] = ld / ADL;
    att[n] = ADL / ld;
}

__global__ void k_scatter(const int* __restrict__ ei, const int* __restrict__ ea,
        int* __restrict__ cursor, int* __restrict__ esrc, int* __restrict__ ecombo){
    int e = blockIdx.x*256 + threadIdx.x;
    if (e >= NE) return;
    int src = ei[e], dst = ei[NE + e];
    int pos = atomicAdd(&cursor[dst], 1);
    esrc[pos] = src;
    ecombo[pos] = ea[2*e]*4 + ea[2*e+1];
}

// R_lut[combo][j] = (e-vector for combo) @ Wc + pre_b  (16x375); block 16 zeroes BN stats
__global__ void k_rlut(const float* __restrict__ edge_emb, const float* __restrict__ encW,
        const float* __restrict__ encb, const float* __restrict__ preW,
        const float* __restrict__ preb, int l, float* __restrict__ Rlut,
        float* __restrict__ stats){
    int b = blockIdx.x, tid = threadIdx.x;
    if (b == 16){
        // BUGFIX: block has 128 threads; stride-loop so all 150 slots get zeroed
        for (int i = tid; i < 150; i += 128) stats[i] = 0.f;
        return;
    }
    int a0 = b >> 2, a1 = b & 3;
    __shared__ float ev[75];
    if (tid < 75){
        int m = tid;
        float s = encb[l*75 + m];
        for (int k = 0; k < 25; k++) s += edge_emb[a0*25+k]*encW[((size_t)l*50+k)*75+m];
        for (int k = 0; k < 25; k++) s += edge_emb[a1*25+k]*encW[((size_t)l*50+25+k)*75+m];
        ev[m] = s;
    }
    __syncthreads();
    for (int j = tid; j < 375; j += 128){
        int t = j/75, f = j - 75*t;
        float r = preb[((size_t)l*NT + t)*75 + f];
        const float* w = preW + (((size_t)(l*NT + t))*225 + 150)*75 + f;
        for (int m = 0; m < 75; m++) r += ev[m]*w[m*75];
        Rlut[b*375 + j] = r;
    }
}

// pad post_W[l] rows to stride 16 (f=15 -> 0) for aligned float4 weight loads
__global__ void k_wprep(const float* __restrict__ postW, int l, float* __restrict__ Wpad){
    int idx = blockIdx.x*256 + threadIdx.x;
    if (idx >= 4875*16) return;
    int r = idx >> 4, f = idx & 15;
    Wpad[idx] = (f < 15) ? postW[(size_t)l*NT*975*15 + r*15 + f] : 0.f;
}

// P = h @ Wa (rows 0..74 of pre_W), Q = h @ Wb (rows 75..149); [10000,75]x[75,375]
__global__ __launch_bounds__(384) void k_pq(const float* __restrict__ h,
        const float* __restrict__ preW, int l, float* __restrict__ P, float* __restrict__ Q){
    __shared__ float h_t[32*76];
    int tid = threadIdx.x;
    int base = blockIdx.x*32;
    for (int idx = tid; idx < 32*75; idx += 384){
        int i = idx/75, m = idx - 75*i;
        int n = base + i;
        h_t[i*76 + m] = (n < NN) ? h[(size_t)n*75 + m] : 0.f;
    }
    __syncthreads();
    int j = tid;
    if (j >= 375) return;
    int t = j/75, f = j - 75*t;
    const float* wbase = preW + ((size_t)(l*NT + t))*225*75 + f;
    float accP[32], accQ[32];
    #pragma unroll
    for (int i = 0; i < 32; i++){ accP[i] = 0.f; accQ[i] = 0.f; }
    for (int m = 0; m < 72; m += 4){
        float wa0 = wbase[(m+0)*75], wa1 = wbase[(m+1)*75];
        float wa2 = wbase[(m+2)*75], wa3 = wbase[(m+3)*75];
        float wb0 = wbase[(75+m+0)*75], wb1 = wbase[(75+m+1)*75];
        float wb2 = wbase[(75+m+2)*75], wb3 = wbase[(75+m+3)*75];
        #pragma unroll
        for (int i = 0; i < 32; i++){
            const float4 hv = *(const float4*)&h_t[i*76 + m];
            accP[i] += hv.x*wa0 + hv.y*wa1 + hv.z*wa2 + hv.w*wa3;
            accQ[i] += hv.x*wb0 + hv.y*wb1 + hv.z*wb2 + hv.w*wb3;
        }
    }
    for (int m = 72; m < 75; m++){
        float wa = wbase[m*75], wb = wbase[(75+m)*75];
        #pragma unroll
        for (int i = 0; i < 32; i++){
            float v = h_t[i*76 + m];
            accP[i] += v*wa; accQ[i] += v*wb;
        }
    }
    for (int i = 0; i < 32; i++){
        int n = base + i;
        if (n < NN){ P[(size_t)n*375 + j] = accP[i]; Q[(size_t)n*375 + j] = accQ[i]; }
    }
}

// one block per node: msgs[e] = P[n] + Q[src] + R_lut[combo]; sum/sumsq/min/max -> agg[N,T,300]
__global__ __launch_bounds__(128) void k_agg(const float* __restrict__ P,
        const float* __restrict__ Q, const float* __restrict__ Rlut,
        const int* __restrict__ eoff, const int* __restrict__ esrc,
        const int* __restrict__ ecombo, const float* __restrict__ invdeg,
        float* __restrict__ agg){
    int n = blockIdx.x, tid = threadIdx.x;
    int lo = eoff[n], hi = eoff[n+1];
    float p[3], sum[3] = {0,0,0}, sq[3] = {0,0,0}, mn[3], mx[3];
    #pragma unroll
    for (int c = 0; c < 3; c++){
        int j = tid + c*128;
        p[c] = (j < 375) ? P[(size_t)n*375 + j] : 0.f;
        mn[c] = 3.4e38f; mx[c] = -3.4e38f;
    }
    for (int e = lo; e < hi; e++){
        int s = esrc[e], cm = ecombo[e];
        const float* q = Q + (size_t)s*375;
        const float* r = Rlut + cm*375;
        #pragma unroll
        for (int c = 0; c < 3; c++){
            int j = tid + c*128;
            if (j < 375){
                float m = p[c] + q[j] + r[j];
                sum[c] += m; sq[c] += m*m;
                mn[c] = fminf(mn[c], m); mx[c] = fmaxf(mx[c], m);
            }
        }
    }
    float id = invdeg[n];
    bool has = hi > lo;
    #pragma unroll
    for (int c = 0; c < 3; c++){
        int j = tid + c*128;
        if (j >= 375) continue;
        float mean = sum[c]*id;
        float msq  = sq[c]*id;
        float var = msq - mean*mean; var = var > 0.f ? var : 0.f;
        float sd = sqrtf(var + 1e-5f);
        float mnv = has ? mn[c] : 0.f;
        float mxv = has ? mx[c] : 0.f;
        int t = j/75, f = j - 75*t;
        float* a = agg + ((size_t)n*NT + t)*300;
        a[f] = mean; a[75+f] = mnv; a[150+f] = mxv; a[225+f] = sd;
    }
}

// post einsum (+bias, amp/att scaling, h-part) fused with lin: hc[N,75]
__global__ __launch_bounds__(128) void k_post(const float* __restrict__ h,
        const float* __restrict__ agg, const float* __restrict__ Wpad,
        const float* __restrict__ postb, const float* __restrict__ linW,
        const float* __restrict__ linb, const float* __restrict__ amp,
        const float* __restrict__ att, int l, float* __restrict__ hc){
    __shared__ float agg_l[8*1500];
    __shared__ float h_l[8*75];
    __shared__ float post_l[8*75];
    int tid = threadIdx.x;
    int base = blockIdx.x*8;
    for (int idx = tid; idx < 8*1500/4; idx += 128)
        ((float4*)agg_l)[idx] = ((const float4*)(agg + (size_t)base*1500))[idx];
    for (int idx = tid; idx < 600; idx += 128)
        h_l[idx] = h[(size_t)base*75 + idx];
    __syncthreads();
    int rep = tid & 7;
    int tp = tid >> 3;
    bool active = tp < 15;
    int t = 0, p = 0;
    float acc[15];
    if (active){
        t = tp % 5; p = tp / 5;
        #pragma unroll
        for (int f = 0; f < 15; f++) acc[f] = 0.f;
        const float* al = agg_l + rep*1500 + t*300;
        if (p == 0){
            const float* hl = h_l + rep*75;
            for (int m = 0; m < 75; m++){
                float v = hl[m];
                const float4* wr = (const float4*)(Wpad + (size_t)(t*975 + m)*16);
                float w[16];
                *(float4*)&w[0] = wr[0]; *(float4*)&w[4] = wr[1];
                *(float4*)&w[8] = wr[2]; *(float4*)&w[12] = wr[3];
                #pragma unroll
                for (int f = 0; f < 15; f++) acc[f] += v*w[f];
            }
        }
        const float* wb = Wpad + (size_t)(t*975 + 75 + p*300)*16;
        for (int k = 0; k < 300; k++){
            float v = al[k];
            const float4* wr = (const float4*)(wb + k*16);
            float w[16];
            *(float4*)&w[0] = wr[0]; *(float4*)&w[4] = wr[1];
            *(float4*)&w[8] = wr[2]; *(float4*)&w[12] = wr[3];
            #pragma unroll
            for (int f = 0; f < 15; f++) acc[f] += v*w[f];
        }
    }
    if (active && p == 0){
        #pragma unroll
        for (int f = 0; f < 15; f++)
            post_l[rep*75 + t*15 + f] = acc[f] + postb[(l*NT + t)*15 + f];
    }
    __syncthreads();
    if (active && p == 1){
        float a_ = amp[base + rep];
        #pragma unroll
        for (int f = 0; f < 15; f++) post_l[rep*75 + t*15 + f] += a_*acc[f];
    }
    __syncthreads();
    if (active && p == 2){
        float a_ = att[base + rep];
        #pragma unroll
        for (int f = 0; f < 15; f++) post_l[rep*75 + t*15 + f] += a_*acc[f];
    }
    __syncthreads();
    // lin: hc = post @ lin_W[l] + lin_b[l]
    for (int task = tid; task < 600; task += 128){
        int i = task/75, o = task - 75*i;
        float s = linb[l*75 + o];
        const float* pl = post_l + i*75;
        const float* w = linW + (size_t)l*75*75 + o;
        #pragma unroll 5
        for (int jj = 0; jj < 75; jj++) s += pl[jj]*w[jj*75];
        hc[(size_t)(base + i)*75 + o] = s;
    }
}

__global__ void k_bnstats(const float* __restrict__ hc, float* __restrict__ stats){
    __shared__ float part[150];
    int tid = threadIdx.x;
    if (tid < 150) part[tid] = 0.f;
    __syncthreads();
    for (size_t idx = blockIdx.x*256 + tid; idx < (size_t)NN*75; idx += (size_t)gridDim.x*256){
        float v = hc[idx];
        int col = (int)(idx % 75);
        atomicAdd(&part[col], v);
        atomicAdd(&part[75 + col], v*v);
    }
    __syncthreads();
    if (tid < 150) atomicAdd(&stats[tid], part[tid]);
}

__global__ void k_bnapply(const float* __restrict__ hc, const float* __restrict__ stats,
        const float* __restrict__ bng, const float* __restrict__ bnb, int l,
        float* __restrict__ h){
    int idx = blockIdx.x*256 + threadIdx.x;
    if (idx >= NN*75) return;
    int col = idx % 75;
    float mu = stats[col]*(1.0f/NN);
    float var = stats[75+col]*(1.0f/NN) - mu*mu;
    float inv = rsqrtf(var + 1e-5f);
    float v = (hc[idx] - mu)*inv*bng[l*75+col] + bnb[l*75+col];
    h[idx] = v > 0.f ? v : 0.f;
}

__global__ __launch_bounds__(256) void k_pool(const float* __restrict__ h,
        const int* __restrict__ batch, float* __restrict__ gpool){
    int g = blockIdx.x, tid = threadIdx.x;
    int lo = 0, hi = NN;
    while (lo < hi){ int mid = (lo+hi)>>1; if (batch[mid] < g) lo = mid+1; else hi = mid; }
    int start = lo;
    lo = start; hi = NN;
    while (lo < hi){ int mid = (lo+hi)>>1; if (batch[mid] < g+1) lo = mid+1; else hi = mid; }
    int end = lo;
    __shared__ float red[225];
    if (tid < 225){
        int col = tid % 75, rep = tid / 75;
        float acc = 0.f;
        for (int i = start + rep; i < end; i += 3) acc += h[(size_t)i*75 + col];
        red[tid] = acc;
    }
    __syncthreads();
    if (tid < 75) gpool[g*75 + tid] = red[tid] + red[75+tid] + red[150+tid];
}

__global__ void k_mlp(const float* __restrict__ gpool,
        const float* __restrict__ W1, const float* __restrict__ b1,
        const float* __restrict__ W2, const float* __restrict__ b2,
        const float* __restrict__ W3, const float* __restrict__ b3,
        float* __restrict__ out){
    int gi = threadIdx.x;
    if (gi >= NG) return;
    const float* gv = gpool + gi*75;
    float t1[50];
    #pragma unroll 2
    for (int j = 0; j < 50; j++){
        float s = b1[j];
        for (int k = 0; k < 75; k++) s += gv[k]*W1[k*50 + j];
        t1[j] = s > 0.f ? s : 0.f;
    }
    float t2[25];
    #pragma unroll
    for (int j = 0; j < 25; j++){
        float s = b2[j];
        for (int k = 0; k < 50; k++) s += t1[k]*W2[k*25 + j];
        t2[j] = s > 0.f ? s : 0.f;
    }
    float s = b3[0];
    for (int k = 0; k < 25; k++) s += t2[k]*W3[k];
    out[gi] = s;
}

extern "C" void kernel_launch(void* const* d_in, const int* in_sizes, int n_in,
                              void* d_out, int out_size, void* d_ws, size_t ws_size,
                              hipStream_t stream){
    const int* x          = (const int*)d_in[0];
    const int* edge_index = (const int*)d_in[1];
    const int* edge_attr  = (const int*)d_in[2];
    const int* batch      = (const int*)d_in[3];
    const float* node_emb = (const float*)d_in[4];
    const float* edge_emb = (const float*)d_in[5];
    const float* pre_lin_W= (const float*)d_in[6];
    const float* pre_lin_b= (const float*)d_in[7];
    const float* encW     = (const float*)d_in[8];
    const float* encb     = (const float*)d_in[9];
    const float* preW     = (const float*)d_in[10];
    const float* preb     = (const float*)d_in[11];
    const float* postW    = (const float*)d_in[12];
    const float* postb    = (const float*)d_in[13];
    const float* linW     = (const float*)d_in[14];
    const float* linb     = (const float*)d_in[15];
    const float* bng      = (const float*)d_in[16];
    const float* bnb      = (const float*)d_in[17];
    const float* mlpW1    = (const float*)d_in[18];
    const float* mlpb1    = (const float*)d_in[19];
    const float* mlpW2    = (const float*)d_in[20];
    const float* mlpb2    = (const float*)d_in[21];
    const float* mlpW3    = (const float*)d_in[22];
    const float* mlpb3    = (const float*)d_in[23];

    float* ws = (float*)d_ws;
    float* h      = ws + OFF_H;
    float* hc     = ws + OFF_HC;
    float* P      = ws + OFF_P;
    float* Q      = ws + OFF_Q;
    float* agg    = ws + OFF_AGG;
    float* Rlut   = ws + OFF_RLUT;
    float* invdeg = ws + OFF_INVDEG;
    float* amp    = ws + OFF_AMP;
    float* att    = ws + OFF_ATT;
    float* stats  = ws + OFF_STATS;
    float* gpool  = ws + OFF_GPOOL;
    float* Wpad   = ws + OFF_WPAD;
    int* iw     = (int*)(ws + OFF_INT);
    int* cnt    = iw;
    int* eoff   = cnt + NN;        // NN+1
    int* cursor = eoff + NN + 2;
    int* esrc   = cursor + NN;
    int* ecombo = esrc + NE;

    k_zero_cnt<<<40, 256, 0, stream>>>(cnt);
    k_h0<<<640, 256, 0, stream>>>(x, node_emb, pre_lin_W, pre_lin_b, h);
    k_hist<<<625, 256, 0, stream>>>(edge_index, cnt);
    k_scan<<<1, 256, 0, stream>>>(cnt, eoff);
    k_nodestats<<<40, 256, 0, stream>>>(cnt, eoff, invdeg, amp, att, cursor);
    k_scatter<<<625, 256, 0, stream>>>(edge_index, edge_attr, cursor, esrc, ecombo);

    for (int l = 0; l < NL; l++){
        k_rlut<<<17, 128, 0, stream>>>(edge_emb, encW, encb, preW, preb, l, Rlut, stats);
        k_wprep<<<305, 256, 0, stream>>>(postW, l, Wpad);
        k_pq<<<313, 384, 0, stream>>>(h, preW, l, P, Q);
        k_agg<<<NN, 128, 0, stream>>>(P, Q, Rlut, eoff, esrc, ecombo, invdeg, agg);
        k_post<<<1250, 128, 0, stream>>>(h, agg, Wpad, postb, linW, linb, amp, att, l, hc);
        k_bnstats<<<128, 256, 0, stream>>>(hc, stats);
        k_bnapply<<<2930, 256, 0, stream>>>(hc, stats, bng, bnb, l, h);
    }

    k_pool<<<NG, 256, 0, stream>>>(h, batch, gpool);
    k_mlp<<<1, 64, 0, stream>>>(gpool, mlpW1, mlpb1, mlpW2, mlpb2, mlpW3, mlpb3, (float*)d_out);
}